// Round 2
// baseline (342.506 us; speedup 1.0000x reference)
//
#include <hip/hip_runtime.h>
#include <math.h>

#define C_CLASSES 32000
#define C4 8000                 // float4 per row
#define BLOCK 1024
#define NWAVES 16
#define NJ 8                    // per-thread float4 slots: 7 full + 1 partial
#define TAIL 832                // C4 - (NJ-1)*BLOCK : threads owning a j==7 element
#define CAP 512                 // active-set capacity (expected ~17/row)
#define GRID 256                // 1 block per CU, 16 rows each, pipelined

__device__ __forceinline__ float wave_sum(float x){
  #pragma unroll
  for (int m = 32; m >= 1; m >>= 1) x += __shfl_xor(x, m, 64);
  return x;
}
__device__ __forceinline__ float wave_max(float x){
  #pragma unroll
  for (int m = 32; m >= 1; m >>= 1) x = fmaxf(x, __shfl_xor(x, m, 64));
  return x;
}

__global__ __launch_bounds__(BLOCK) void sparsemax_loss_kernel(
    const float* __restrict__ input,
    const float* __restrict__ target,
    const float* __restrict__ weight,
    float* __restrict__ rowloss, int B, int rowsPer)
{
  __shared__ float s_act[CAP];     // active-set z values
  __shared__ float s_aw[CAP];      // matching weights
  __shared__ float s_red[NWAVES];
  __shared__ float s_red2[NWAVES];
  __shared__ float s_bcast;
  __shared__ float s_tau;
  __shared__ float s_corr;
  __shared__ int   s_cnt;
  __shared__ int   s_flag;

  const int tid  = threadIdx.x;
  const int lane = tid & 63;
  const int wid  = tid >> 6;
  const int row0 = blockIdx.x * rowsPer;
  if (row0 >= B) return;
  const int nr   = min(rowsPer, B - row0);
  const bool tact = (tid < TAIL);

  // ---- register-resident row buffer; prologue: prefetch first row ----
  float4 vin[NJ];
  #pragma unroll
  for (int j = 0; j < NJ; ++j)
    vin[j] = make_float4(-3.0e38f, -3.0e38f, -3.0e38f, -3.0e38f);
  {
    const float4* p0 = (const float4*)(input + (size_t)row0 * C_CLASSES);
    #pragma unroll
    for (int j = 0; j < NJ; ++j){
      const int i = tid + j * BLOCK;
      if (j < NJ - 1 || tact) vin[j] = p0[i];
    }
  }

  for (int r = 0; r < nr; ++r){
    const int row = row0 + r;

    // ---- phase A: row max (registers -> wave shuffle -> LDS) ----
    float mx = -3.0e38f;
    #pragma unroll
    for (int j = 0; j < NJ; ++j){
      float4 v = vin[j];
      mx = fmaxf(mx, fmaxf(fmaxf(v.x, v.y), fmaxf(v.z, v.w)));
    }
    mx = wave_max(mx);
    if (lane == 0) s_red[wid] = mx;
    if (tid == 0){ s_cnt = 0; s_flag = 0; s_corr = 0.0f; }
    __syncthreads();
    if (tid < 64){
      float x = (lane < NWAVES) ? s_red[lane] : -3.0e38f;
      x = wave_max(x);
      if (lane == 0) s_bcast = x;
    }
    __syncthreads();
    const float m = s_bcast;

    // ---- phase B: collect active set {z > -1} from registers ----
    // tau* solves sum(max(z-tau,0))=1 with max(z)=0  =>  tau* in [-1, 0)
    #pragma unroll
    for (int j = 0; j < NJ; ++j){
      if (j < NJ - 1 || tact){
        float4 v = vin[j];
        const int idx0 = (tid + j * BLOCK) * 4;
        float z;
        z = v.x - m; if (z > -1.0f){ int p = atomicAdd(&s_cnt, 1); if (p < CAP){ s_act[p] = z; s_aw[p] = weight[idx0 + 0]; } }
        z = v.y - m; if (z > -1.0f){ int p = atomicAdd(&s_cnt, 1); if (p < CAP){ s_act[p] = z; s_aw[p] = weight[idx0 + 1]; } }
        z = v.z - m; if (z > -1.0f){ int p = atomicAdd(&s_cnt, 1); if (p < CAP){ s_act[p] = z; s_aw[p] = weight[idx0 + 2]; } }
        z = v.w - m; if (z > -1.0f){ int p = atomicAdd(&s_cnt, 1); if (p < CAP){ s_act[p] = z; s_aw[p] = weight[idx0 + 3]; } }
      }
    }
    __syncthreads();
    const int cnt = s_cnt;
    const bool fb = (cnt > CAP);   // uniform

    if (fb){
      // ---- fallback: block-wide Michelot from registers (runs BEFORE the
      // main pass clobbers vin with the prefetch). Correctness-only path. ----
      float t = -1.0f;
      for (int it = 0; it < 100000; ++it){
        float s = 0.0f, k = 0.0f;
        #pragma unroll
        for (int j = 0; j < NJ; ++j){
          if (j < NJ - 1 || tact){
            float4 v = vin[j]; float z;
            z = v.x - m; if (z > t){ s += z; k += 1.0f; }
            z = v.y - m; if (z > t){ s += z; k += 1.0f; }
            z = v.z - m; if (z > t){ s += z; k += 1.0f; }
            z = v.w - m; if (z > t){ s += z; k += 1.0f; }
          }
        }
        s = wave_sum(s); k = wave_sum(k);
        if (lane == 0){ s_red[wid] = s; s_red2[wid] = k; }
        __syncthreads();
        if (tid == 0){
          float S = 0.0f, K = 0.0f;
          for (int w = 0; w < NWAVES; ++w){ S += s_red[w]; K += s_red2[w]; }
          float tn = (S - 1.0f) / K;
          if (!(tn > t)) s_flag = 1; else s_bcast = tn;
        }
        __syncthreads();
        if (s_flag) break;     // uniform
        t = s_bcast;
      }
      const float4* wp = (const float4*)weight;
      const float t2 = t * t;
      float corr = 0.0f;
      #pragma unroll
      for (int j = 0; j < NJ; ++j){
        const int i = tid + j * BLOCK;
        if (j < NJ - 1 || tact){
          float4 v = vin[j]; float4 w4v = wp[i]; float z;
          z = v.x - m; if (z > t) corr += w4v.x * (z*z - t2);
          z = v.y - m; if (z > t) corr += w4v.y * (z*z - t2);
          z = v.z - m; if (z > t) corr += w4v.z * (z*z - t2);
          z = v.w - m; if (z > t) corr += w4v.w * (z*z - t2);
        }
      }
      corr = wave_sum(corr);
      if (lane == 0) atomicAdd(&s_corr, corr);
      if (tid == 0) s_tau = t;
      __syncthreads();
    }

    // ---- phase C: tau-independent main sum + prefetch next row's input ----
    // rowloss = sum w*(0.5 z^2 + 0.5 t^2 - t z)  - 0.5 tau^2 * sum w
    //           - 0.5 * sum_{z>tau} w*(z^2 - tau^2)
    const float4* tg = (const float4*)(target + (size_t)row * C_CLASSES);
    const float4* wp = (const float4*)weight;
    const float4* pn = (r + 1 < nr)
        ? (const float4*)(input + (size_t)(row + 1) * C_CLASSES)
        : (const float4*)0;
    float acc = 0.0f, sw = 0.0f;
    #pragma unroll
    for (int j = 0; j < NJ; ++j){
      const int i = tid + j * BLOCK;
      if (j < NJ - 1 || tact){
        float4 v = vin[j];
        float4 t4 = tg[i];
        float4 w4v = wp[i];
        float z, t, w;
        z = v.x - m; t = t4.x; w = w4v.x; acc += w * (0.5f*(z*z + t*t) - t*z); sw += w;
        z = v.y - m; t = t4.y; w = w4v.y; acc += w * (0.5f*(z*z + t*t) - t*z); sw += w;
        z = v.z - m; t = t4.z; w = w4v.z; acc += w * (0.5f*(z*z + t*t) - t*z); sw += w;
        z = v.w - m; t = t4.w; w = w4v.w; acc += w * (0.5f*(z*z + t*t) - t*z); sw += w;
        if (pn) vin[j] = pn[i];     // prefetch row r+1 while Newton runs below
      }
    }
    acc = wave_sum(acc); sw = wave_sum(sw);
    if (lane == 0){ s_red[wid] = acc; s_red2[wid] = sw; }
    __syncthreads();

    if (!fb){
      // ---- phase D: wave-0 Michelot on the tiny active set + finalize.
      // Other waves fall to the barrier; their prefetch loads are in flight. ----
      if (wid == 0){
        float t = -1.0f;
        for (int it = 0; it < 100000; ++it){
          float s = 0.0f, k = 0.0f;
          for (int i = lane; i < cnt; i += 64){
            float z = s_act[i];
            if (z > t){ s += z; k += 1.0f; }
          }
          s = wave_sum(s); k = wave_sum(k);
          float tn = (s - 1.0f) / k;   // k>=1 always (z_max=0 > t)
          if (!(tn > t)) break;        // monotone from below -> exact fixpoint
          t = tn;
        }
        const float t2 = t * t;
        float corr = 0.0f;
        for (int i = lane; i < cnt; i += 64){
          float z = s_act[i];
          if (z > t) corr += s_aw[i] * (z*z - t2);
        }
        corr = wave_sum(corr);
        if (lane == 0){
          float A = 0.0f, W = 0.0f;
          for (int w = 0; w < NWAVES; ++w){ A += s_red[w]; W += s_red2[w]; }
          rowloss[row] = A - 0.5f * t2 * W - 0.5f * corr;
        }
      }
    } else {
      if (tid == 0){
        float A = 0.0f, W = 0.0f;
        for (int w = 0; w < NWAVES; ++w){ A += s_red[w]; W += s_red2[w]; }
        const float t2 = s_tau * s_tau;
        rowloss[row] = A - 0.5f * t2 * W - 0.5f * s_corr;
      }
    }
    __syncthreads();   // protect s_red/s_act for next row
  }
}

__global__ __launch_bounds__(1024) void reduce_mean_kernel(
    const float* __restrict__ rowloss, float* __restrict__ out, int B)
{
  __shared__ float s_red[16];
  const int tid  = threadIdx.x;
  const int lane = tid & 63;
  const int wid  = tid >> 6;
  float acc = 0.0f;
  for (int i = tid; i < B; i += 1024) acc += rowloss[i];
  acc = wave_sum(acc);
  if (lane == 0) s_red[wid] = acc;
  __syncthreads();
  if (tid < 64){
    float x = (lane < 16) ? s_red[lane] : 0.0f;
    x = wave_sum(x);
    if (lane == 0) out[0] = x / (float)B;
  }
}

extern "C" void kernel_launch(void* const* d_in, const int* in_sizes, int n_in,
                              void* d_out, int out_size, void* d_ws, size_t ws_size,
                              hipStream_t stream)
{
  const float* input  = (const float*)d_in[0];
  const float* target = (const float*)d_in[1];
  const float* weight = (const float*)d_in[2];
  float* out     = (float*)d_out;
  float* rowloss = (float*)d_ws;

  const int C = in_sizes[2];           // 32000
  const int B = in_sizes[0] / C;       // 4096
  const int rowsPer = (B + GRID - 1) / GRID;

  sparsemax_loss_kernel<<<GRID, BLOCK, 0, stream>>>(input, target, weight, rowloss, B, rowsPer);
  reduce_mean_kernel<<<1, 1024, 0, stream>>>(rowloss, out, B);
}

// Round 3
// 192.751 us; speedup vs baseline: 1.7769x; 1.7769x over previous
//
#include <hip/hip_runtime.h>
#include <math.h>

#define C_CLASSES 32000
#define C4 8000                 // float4 per row
#define BLOCK 512
#define NWAVES 8
#define FULL_ITERS 15           // 15*512 = 7680 float4
#define TAIL_N 320              // 8000 - 7680
#define CAP 2048                // candidate capacity (expect ~330)

__device__ __forceinline__ float wave_sum(float x){
  #pragma unroll
  for (int m = 32; m >= 1; m >>= 1) x += __shfl_xor(x, m, 64);
  return x;
}
__device__ __forceinline__ float wave_max(float x){
  #pragma unroll
  for (int m = 32; m >= 1; m >>= 1) x = fmaxf(x, __shfl_xor(x, m, 64));
  return x;
}

__global__ __launch_bounds__(BLOCK) void sparsemax_fused_kernel(
    const float* __restrict__ input,
    const float* __restrict__ target,
    const float* __restrict__ weight,
    float* __restrict__ rowloss)
{
  __shared__ float s_val[CAP];      // candidate raw x values
  __shared__ int   s_idx[CAP];      // candidate class indices (for weight)
  __shared__ float sA[NWAVES], sBx[NWAVES], sBt[NWAVES], sW[NWAVES], sM[NWAVES];
  __shared__ float s_thr;           // seed threshold, later Michelot broadcast
  __shared__ float s_m, s_base;     // rowmax, max-free combined sum
  __shared__ float s_sw;            // total weight sum broadcast
  __shared__ int   s_cnt;
  __shared__ int   s_flag;

  const int row  = blockIdx.x;
  const int tid  = threadIdx.x;
  const int lane = tid & 63;
  const int wid  = tid >> 6;

  const float4* in4 = (const float4*)(input  + (size_t)row * C_CLASSES);
  const float4* tg4 = (const float4*)(target + (size_t)row * C_CLASSES);
  const float4* wt4 = (const float4*)weight;

  // ---- seed: max of first 2048 elements -> conservative threshold ----
  float4 v0 = in4[tid];
  float lm = fmaxf(fmaxf(v0.x, v0.y), fmaxf(v0.z, v0.w));
  float wmx = wave_max(lm);
  if (lane == 0) sM[wid] = wmx;
  if (tid == 0){ s_cnt = 0; s_flag = 0; }
  __syncthreads();
  if (tid == 0){
    float t = sM[0];
    #pragma unroll
    for (int w = 1; w < NWAVES; ++w) t = fmaxf(t, sM[w]);
    s_thr = t - 1.0f;   // seed_max <= rowmax  =>  {x>thr} superset of active set
  }
  __syncthreads();
  const float thr = s_thr;

  // ---- single streaming pass: max-free sums + rowmax + candidates ----
  // base = sum w*(0.5 z^2 + 0.5 t^2 - t z)
  //      = A - m*Bx + 0.5 m^2 * Sw + m*Bt   with z = x - m
  float A = 0.0f, Bx = 0.0f, Bt = 0.0f, Sw = 0.0f, rm = lm;

#define PROC(xc, tc, wc, gidx)                                               \
  {                                                                          \
    float x = (xc), t = (tc), w = (wc);                                      \
    A  += w * (0.5f * (x * x + t * t) - t * x);                              \
    Bx += w * x;  Bt += w * t;  Sw += w;                                     \
    if (x > thr){                                                            \
      int p = atomicAdd(&s_cnt, 1);                                          \
      if (p < CAP){ s_val[p] = x; s_idx[p] = (gidx); }                       \
    }                                                                        \
  }

  // stashed first iteration
  {
    float4 t4 = tg4[tid]; float4 w4 = wt4[tid];
    const int gi = tid * 4;
    PROC(v0.x, t4.x, w4.x, gi + 0)
    PROC(v0.y, t4.y, w4.y, gi + 1)
    PROC(v0.z, t4.z, w4.z, gi + 2)
    PROC(v0.w, t4.w, w4.w, gi + 3)
  }
  #pragma unroll 2
  for (int j = 1; j < FULL_ITERS; ++j){
    const int i = tid + j * BLOCK;
    float4 v = in4[i]; float4 t4 = tg4[i]; float4 w4 = wt4[i];
    rm = fmaxf(rm, fmaxf(fmaxf(v.x, v.y), fmaxf(v.z, v.w)));
    const int gi = i * 4;
    PROC(v.x, t4.x, w4.x, gi + 0)
    PROC(v.y, t4.y, w4.y, gi + 1)
    PROC(v.z, t4.z, w4.z, gi + 2)
    PROC(v.w, t4.w, w4.w, gi + 3)
  }
  if (tid < TAIL_N){
    const int i = FULL_ITERS * BLOCK + tid;   // 7680 + tid
    float4 v = in4[i]; float4 t4 = tg4[i]; float4 w4 = wt4[i];
    rm = fmaxf(rm, fmaxf(fmaxf(v.x, v.y), fmaxf(v.z, v.w)));
    const int gi = i * 4;
    PROC(v.x, t4.x, w4.x, gi + 0)
    PROC(v.y, t4.y, w4.y, gi + 1)
    PROC(v.z, t4.z, w4.z, gi + 2)
    PROC(v.w, t4.w, w4.w, gi + 3)
  }
#undef PROC

  // ---- block reductions ----
  rm = wave_max(rm);
  A = wave_sum(A); Bx = wave_sum(Bx); Bt = wave_sum(Bt); Sw = wave_sum(Sw);
  if (lane == 0){ sM[wid] = rm; sA[wid] = A; sBx[wid] = Bx; sBt[wid] = Bt; sW[wid] = Sw; }
  __syncthreads();
  if (tid == 0){
    float m8 = sM[0], A8 = sA[0], Bx8 = sBx[0], Bt8 = sBt[0], Sw8 = sW[0];
    #pragma unroll
    for (int w = 1; w < NWAVES; ++w){
      m8 = fmaxf(m8, sM[w]); A8 += sA[w]; Bx8 += sBx[w]; Bt8 += sBt[w]; Sw8 += sW[w];
    }
    s_m    = m8;
    s_base = A8 - m8 * Bx8 + 0.5f * m8 * m8 * Sw8 + m8 * Bt8;
    s_sw   = Sw8;
  }
  __syncthreads();
  const float m    = s_m;
  const float base = s_base;
  const float sw8  = s_sw;
  const int   cnt  = s_cnt;

  if (cnt <= CAP){
    // ---- wave-0 Michelot on candidates (tau* in [-1,0); candidates superset) ----
    if (wid == 0){
      float t = -1.0f;
      for (int it = 0; it < 200; ++it){
        float s = 0.0f, k = 0.0f;
        for (int i = lane; i < cnt; i += 64){
          float z = s_val[i] - m;
          if (z > t){ s += z; k += 1.0f; }
        }
        s = wave_sum(s); k = wave_sum(k);
        float tn = (s - 1.0f) / k;        // k>=1: the max element (z=0) always > t
        if (!(tn > t)) break;             // monotone from below -> exact fixpoint
        t = tn;
      }
      const float t2 = t * t;
      float corr = 0.0f;
      for (int i = lane; i < cnt; i += 64){
        float z = s_val[i] - m;
        if (z > t) corr += weight[s_idx[i]] * (z * z - t2);
      }
      corr = wave_sum(corr);
      if (lane == 0)
        rowloss[row] = base - 0.5f * t2 * sw8 - 0.5f * corr;
    }
  } else {
    // ---- fallback: block-wide Michelot over global row (L3-resident). ----
    const float* inf = input + (size_t)row * C_CLASSES;
    float t = -1.0f;
    for (int it = 0; it < 200; ++it){
      float s = 0.0f, k = 0.0f;
      for (int i = tid; i < C_CLASSES; i += BLOCK){
        float z = inf[i] - m;
        if (z > t){ s += z; k += 1.0f; }
      }
      s = wave_sum(s); k = wave_sum(k);
      if (lane == 0){ sA[wid] = s; sBx[wid] = k; }
      __syncthreads();
      if (tid == 0){
        float S = 0.0f, K = 0.0f;
        for (int w = 0; w < NWAVES; ++w){ S += sA[w]; K += sBx[w]; }
        float tn = (S - 1.0f) / K;
        if (!(tn > t)) s_flag = 1; else s_thr = tn;
      }
      __syncthreads();
      if (s_flag) break;    // uniform
      t = s_thr;
    }
    const float t2 = t * t;
    float corr = 0.0f;
    for (int i = tid; i < C_CLASSES; i += BLOCK){
      float z = inf[i] - m;
      if (z > t) corr += weight[i] * (z * z - t2);
    }
    corr = wave_sum(corr);
    if (lane == 0) sA[wid] = corr;
    __syncthreads();
    if (tid == 0){
      float C8 = 0.0f;
      for (int w = 0; w < NWAVES; ++w) C8 += sA[w];
      rowloss[row] = base - 0.5f * t2 * sw8 - 0.5f * C8;
    }
  }
}

__global__ __launch_bounds__(1024) void reduce_mean_kernel(
    const float* __restrict__ rowloss, float* __restrict__ out, int B)
{
  __shared__ float s_red[16];
  const int tid  = threadIdx.x;
  const int lane = tid & 63;
  const int wid  = tid >> 6;
  float acc = 0.0f;
  for (int i = tid; i < B; i += 1024) acc += rowloss[i];
  acc = wave_sum(acc);
  if (lane == 0) s_red[wid] = acc;
  __syncthreads();
  if (tid < 64){
    float x = (lane < 16) ? s_red[lane] : 0.0f;
    x = wave_sum(x);
    if (lane == 0) out[0] = x / (float)B;
  }
}

extern "C" void kernel_launch(void* const* d_in, const int* in_sizes, int n_in,
                              void* d_out, int out_size, void* d_ws, size_t ws_size,
                              hipStream_t stream)
{
  const float* input  = (const float*)d_in[0];
  const float* target = (const float*)d_in[1];
  const float* weight = (const float*)d_in[2];
  float* out     = (float*)d_out;
  float* rowloss = (float*)d_ws;

  const int C = in_sizes[2];           // 32000
  const int B = in_sizes[0] / C;       // 4096

  sparsemax_fused_kernel<<<B, BLOCK, 0, stream>>>(input, target, weight, rowloss);
  reduce_mean_kernel<<<1, 1024, 0, stream>>>(rowloss, out, B);
}